// Round 6
// baseline (355.091 us; speedup 1.0000x reference)
//
#include <hip/hip_runtime.h>

// FeatureCorrelation: B=8192 rows x 3 steps x D=2048 fp32.
// 201 MB in + 201 MB out; floor ~64 us @ 6.3 TB/s achievable.
//
// R9: R8 with doubled wave count (single-variable A/B: blocks 512 -> 1024).
// Evidence trail:
//  - R4 (121us, 2.4 TB/s): wave/row burst, 16 waves/CU, bulk-sync.
//  - R5 (144us): 2-row reg ping-pong -> spill (FETCH/WRITE +47MB).
//  - R6 two-pass: K1 reduce 143us @1.5 (window strangled); K2 combine ~82us
//    @~4.9 (rolling loads+stores, high occupancy).
//  - R8 (127us, 3.15 TB/s): fused reduce||combine stream, 512 blocks.
//    FETCH=196MB proves the L3-mediated re-read works (input crosses HBM once).
//    But 8 waves/CU x 1-iter effective window -> each j-iter pays ~2x 900cy
//    latency serially -> ~1800cy/iter/wave -> 3.15 TB/s.
//  => Need continuity (R8 has it) AND wave-level parallelism (R8 lacks it).
// This round: 1024 blocks = 16 waves/CU, 2 rows/wave. Same code otherwise.
// L3-churn check: ~4096 waves x 24KB pending + ~98MB output ~ 200MB < 256MB L3,
// borderline -- if FETCH jumps above ~250MB, L3 lost the pending rows and we
// drop to 768 blocks or chunk-fuse in L2 next.

constexpr int D   = 2048;
constexpr int TPB = 256;                 // 4 waves per block
constexpr int WPB = TPB / 64;
constexpr int NC  = D / (64 * 4);        // 8 fvec4 chunks per vector per lane
constexpr float EPS_PD = 1e-6f;
constexpr float EPS_CS = 1e-8f;

using fvec4 = __attribute__((ext_vector_type(4))) float;

__global__ __launch_bounds__(TPB, 4) void feat_corr_fused(
    const float* __restrict__ feat,
    const float* __restrict__ pos,
    float* __restrict__ out,
    int B, int NW)                       // NW = total waves in grid
{
    // pos (24 KB) in LDS once per block: pos reads use the lgkm queue and
    // never perturb the global-load window.
    __shared__ float psh[3 * D];
    {
        const fvec4* ps = (const fvec4*)pos;
        fvec4*       pd = (fvec4*)psh;
#pragma unroll
        for (int i = threadIdx.x; i < 3 * D / 4; i += TPB) pd[i] = ps[i];
    }
    __syncthreads();                     // only barrier; no barriers after

    const int lane = threadIdx.x & 63;
    const int gw   = blockIdx.x * WPB + (threadIdx.x >> 6);
    if (gw >= B) return;

    const fvec4* p1 = (const fvec4*)psh;
    const fvec4* p2 = p1 + D / 4;
    const fvec4* p3 = p2 + D / 4;

    // Butterfly + weights -> 6 combine coefficients.
    // eps cross-term 2*EPS_PD*(Si-Sj) dropped (~1e-9 relative; verified
    // passing R6/R8). Weights symmetric: wij == wji.
    auto finalize = [&](float v[6], float cf[6]) {
#pragma unroll
        for (int off = 1; off < 64; off <<= 1)
#pragma unroll
            for (int k = 0; k < 6; ++k) v[k] += __shfl_xor(v[k], off, 64);
        const float N1s = v[0], N2s = v[1], N3s = v[2];
        const float D12 = v[3], D13 = v[4], D23 = v[5];
        const float n1 = fmaxf(sqrtf(N1s), EPS_CS);
        const float n2 = fmaxf(sqrtf(N2s), EPS_CS);
        const float n3 = fmaxf(sqrtf(N3s), EPS_CS);
        const float c12 = 0.5f + 0.5f * (D12 / (n1 * n2));
        const float c13 = 0.5f + 0.5f * (D13 / (n1 * n3));
        const float c23 = 0.5f + 0.5f * (D23 / (n2 * n3));
        const float De2 = (float)D * EPS_PD * EPS_PD;
        const float w12 = 1.f / (1.f + sqrtf(N1s + N2s - 2.f * D12 + De2));
        const float w13 = 1.f / (1.f + sqrtf(N1s + N3s - 2.f * D13 + De2));
        const float w23 = 1.f / (1.f + sqrtf(N2s + N3s - 2.f * D23 + De2));
        cf[0] = w12 + c12;  // g1b   o1 = x1 + g1b*x2 + g1c*x3
        cf[1] = w13 + c13;  // g1c
        cf[2] = w12 + c12;  // g2a   o2 = x2 + g2a*x1 + g2c*x3
        cf[3] = w23 + c23;  // g2c
        cf[4] = w13 + c13;  // g3a   o3 = x3 + g3a*x1 + g3b*x2
        cf[5] = w23 + c23;  // g3b
    };

    // ---- Prologue: pure reduce of this wave's first row.
    int rp = gw;                          // row with combine pending
    float cf[6];
    {
        const fvec4* a1 = (const fvec4*)(feat + (size_t)rp * (3 * D));
        const fvec4* a2 = a1 + D / 4;
        const fvec4* a3 = a2 + D / 4;
        float acc[6] = {0.f, 0.f, 0.f, 0.f, 0.f, 0.f};
#pragma unroll 2
        for (int j = 0; j < NC; ++j) {
            const int idx = j * 64 + lane;
            const fvec4 u = a1[idx] + p1[idx];
            const fvec4 w = a2[idx] + p2[idx];
            const fvec4 z = a3[idx] + p3[idx];
#pragma unroll
            for (int k = 0; k < 4; ++k) {
                acc[0] = fmaf(u[k], u[k], acc[0]);
                acc[1] = fmaf(w[k], w[k], acc[1]);
                acc[2] = fmaf(z[k], z[k], acc[2]);
                acc[3] = fmaf(u[k], w[k], acc[3]);
                acc[4] = fmaf(u[k], z[k], acc[4]);
                acc[5] = fmaf(w[k], z[k], acc[5]);
            }
        }
        finalize(acc, cf);
    }

    // ---- Steady state: reduce row r  ||  combine+store row rp (cache-hot).
    for (int r = rp + NW; r < B; r += NW) {
        const fvec4* a1 = (const fvec4*)(feat + (size_t)r  * (3 * D));
        const fvec4* a2 = a1 + D / 4;
        const fvec4* a3 = a2 + D / 4;
        const fvec4* b1 = (const fvec4*)(feat + (size_t)rp * (3 * D));
        const fvec4* b2 = b1 + D / 4;
        const fvec4* b3 = b2 + D / 4;
        fvec4* o1 = (fvec4*)(out + (size_t)rp * (3 * D));
        fvec4* o2 = o1 + D / 4;
        fvec4* o3 = o2 + D / 4;
        const float g1b = cf[0], g1c = cf[1], g2a = cf[2];
        const float g2c = cf[3], g3a = cf[4], g3b = cf[5];

        float acc[6] = {0.f, 0.f, 0.f, 0.f, 0.f, 0.f};
#pragma unroll 2
        for (int j = 0; j < NC; ++j) {
            const int idx = j * 64 + lane;
            const fvec4 q1 = p1[idx], q2 = p2[idx], q3 = p3[idx];
            const fvec4 u  = a1[idx] + q1;        // new row: HBM stream
            const fvec4 w  = a2[idx] + q2;
            const fvec4 z  = a3[idx] + q3;
            const fvec4 x1 = b1[idx] + q1;        // pending row: L3-hot re-read
            const fvec4 x2 = b2[idx] + q2;
            const fvec4 x3 = b3[idx] + q3;
#pragma unroll
            for (int k = 0; k < 4; ++k) {
                acc[0] = fmaf(u[k], u[k], acc[0]);
                acc[1] = fmaf(w[k], w[k], acc[1]);
                acc[2] = fmaf(z[k], z[k], acc[2]);
                acc[3] = fmaf(u[k], w[k], acc[3]);
                acc[4] = fmaf(u[k], z[k], acc[4]);
                acc[5] = fmaf(w[k], z[k], acc[5]);
            }
            __builtin_nontemporal_store(x1 + g1b * x2 + g1c * x3, o1 + idx);
            __builtin_nontemporal_store(x2 + g2a * x1 + g2c * x3, o2 + idx);
            __builtin_nontemporal_store(x3 + g3a * x1 + g3b * x2, o3 + idx);
        }
        finalize(acc, cf);
        rp = r;
    }

    // ---- Epilogue: combine the last pending row.
    {
        const fvec4* b1 = (const fvec4*)(feat + (size_t)rp * (3 * D));
        const fvec4* b2 = b1 + D / 4;
        const fvec4* b3 = b2 + D / 4;
        fvec4* o1 = (fvec4*)(out + (size_t)rp * (3 * D));
        fvec4* o2 = o1 + D / 4;
        fvec4* o3 = o2 + D / 4;
        const float g1b = cf[0], g1c = cf[1], g2a = cf[2];
        const float g2c = cf[3], g3a = cf[4], g3b = cf[5];
#pragma unroll 2
        for (int j = 0; j < NC; ++j) {
            const int idx = j * 64 + lane;
            const fvec4 q1 = p1[idx], q2 = p2[idx], q3 = p3[idx];
            const fvec4 x1 = b1[idx] + q1;
            const fvec4 x2 = b2[idx] + q2;
            const fvec4 x3 = b3[idx] + q3;
            __builtin_nontemporal_store(x1 + g1b * x2 + g1c * x3, o1 + idx);
            __builtin_nontemporal_store(x2 + g2a * x1 + g2c * x3, o2 + idx);
            __builtin_nontemporal_store(x3 + g3a * x1 + g3b * x2, o3 + idx);
        }
    }
}

extern "C" void kernel_launch(void* const* d_in, const int* in_sizes, int n_in,
                              void* d_out, int out_size, void* d_ws, size_t ws_size,
                              hipStream_t stream) {
    const float* feat = (const float*)d_in[0];
    const float* pos  = (const float*)d_in[1];
    float* out        = (float*)d_out;
    const int B = in_sizes[0] / (3 * D);     // rows (element-count semantics, verified)

    // 1024 blocks x 4 waves = 4096 waves = 16 waves/CU (VGPR 64, LDS 96KB/CU:
    // nothing binds). 2 rows/wave: prologue-reduce + 1 fused iter + epilogue.
    int blocks = 1024;
    if (blocks * WPB > B) blocks = (B + WPB - 1) / WPB;
    const int NW = blocks * WPB;
    feat_corr_fused<<<blocks, TPB, 0, stream>>>(feat, pos, out, B, NW);
}